// Round 7
// baseline (80.997 us; speedup 1.0000x reference)
//
#include <hip/hip_runtime.h>

// Mixture-of-64-tiny-experts, fp32, packed-pair (2 samples in v2f halves).
// R6: validated cycle model (2cyc/pk-VALU, 16cyc/scalar-trans, issue-blocking)
// says 78% of issue time was v_exp/v_rcp. Replace activation tanh with PACKED
// Pade[5/4] + bit-hack+1-Newton packed reciprocal (zero trans per activation);
// only the softmax exp2 (needs real range) stays on the trans pipe.
// Structure = R4 (best so far): 2 samples/thread, all 64 subnets per thread.

#define NSUB 64
#define L2E  1.4426950408889634f   // log2(e)

typedef float v2f __attribute__((ext_vector_type(2)));

__device__ __forceinline__ v2f pk_fma(v2f a, v2f b, v2f c) {
    return __builtin_elementwise_fma(a, b, c);
}
__device__ __forceinline__ v2f sp(float s) { return v2f{s, s}; }

// packed positive reciprocal: bit-hack seed + 1 Newton iter (~1.1e-3 rel err)
__device__ __forceinline__ v2f pk_rcp1(v2f d) {
    v2f r;
    r.x = __int_as_float(0x7EF311C3 - __float_as_int(d.x));
    r.y = __int_as_float(0x7EF311C3 - __float_as_int(d.y));
    r = r * pk_fma(-d, r, sp(2.0f));
    return r;
}

// packed tanh via Pade[5/4] + clamp. |err| <~ 2.3e-3 incl. rcp error.
// tanh(x) ~= x*(945 + 105 t + t^2) / (945 + 420 t + 15 t^2), t = x^2;
// ratio >= 1-3e-5 for |x|>=3.7 and monotone above -> med3 clamp exact there.
__device__ __forceinline__ v2f tanh_pade_v(v2f x) {
    v2f t = x * x;
    v2f n = pk_fma(t, t + 105.0f, sp(945.0f));
    v2f d = pk_fma(t, pk_fma(t, sp(15.0f), sp(420.0f)), sp(945.0f));
    v2f u = (x * n) * pk_rcp1(d);
    v2f r;
    r.x = __builtin_amdgcn_fmed3f(u.x, -1.0f, 1.0f);
    r.y = __builtin_amdgcn_fmed3f(u.y, -1.0f, 1.0f);
    return r;
}

__device__ __forceinline__ v2f tanhshrink_v(v2f x) {
    return x - tanh_pade_v(x);
}

// Packed per-subnet params as DUPLICATED PAIRS, 96 floats (48 pair-slots):
// pair idx: [0:24) W1 (4x6) | [24:28) b1 | [28:36) W2 (2x4) | [36:38) b2
//           [38:44) Gw2*L2E | [44] Gb2*L2E | [45:48) pad
__global__ void pack_kernel(const float* __restrict__ W1, const float* __restrict__ b1,
                            const float* __restrict__ W2, const float* __restrict__ b2,
                            const float* __restrict__ Gw2, const float* __restrict__ Gb2,
                            float* __restrict__ ws)
{
    int s = threadIdx.x;
    if (s >= NSUB) return;
    float* f = ws + s * 96;
    for (int i = 0; i < 24; ++i) { float v = W1[s * 24 + i];       f[2*i] = v;      f[2*i+1] = v; }
    for (int i = 0; i < 4;  ++i) { float v = b1[s * 4 + i];        f[48+2*i] = v;   f[48+2*i+1] = v; }
    for (int i = 0; i < 8;  ++i) { float v = W2[s * 8 + i];        f[56+2*i] = v;   f[56+2*i+1] = v; }
    for (int i = 0; i < 2;  ++i) { float v = b2[s * 2 + i];        f[72+2*i] = v;   f[72+2*i+1] = v; }
    for (int i = 0; i < 6;  ++i) { float v = Gw2[s * 6 + i] * L2E; f[76+2*i] = v;   f[76+2*i+1] = v; }
    { float v = Gb2[s] * L2E; f[88] = v; f[89] = v; }
    f[90] = 0.f; f[91] = 0.f; f[92] = 0.f; f[93] = 0.f; f[94] = 0.f; f[95] = 0.f;
}

__global__ __launch_bounds__(256) void moe_kernel(
    const float* __restrict__ x,
    const float* __restrict__ wpack,
    const float* __restrict__ Gw1, const float* __restrict__ Gb1,
    float* __restrict__ out)
{
    long t = blockIdx.x * blockDim.x + threadIdx.x;

    // two adjacent samples per thread: 12 floats = 3 x float4 (48B stride)
    const float4* xv = (const float4*)(x + t * 12);
    float4 a0 = xv[0];
    float4 a1 = xv[1];
    float4 a2 = xv[2];
    v2f xa[6] = { v2f{a0.x, a1.z}, v2f{a0.y, a1.w}, v2f{a0.z, a2.x},
                  v2f{a0.w, a2.y}, v2f{a1.x, a2.z}, v2f{a1.y, a2.w} };

    // ---- gating hidden: g = tanhshrink(Gw1 @ x + Gb1) ----
    v2f ga[6];
#pragma unroll
    for (int j = 0; j < 6; ++j) {
        v2f s = sp(Gb1[j]);
#pragma unroll
        for (int i = 0; i < 6; ++i)
            s = pk_fma(sp(Gw1[j * 6 + i]), xa[i], s);
        ga[j] = tanhshrink_v(s);
    }

    // ---- subnet loop, softmax folded into running num/denom ----
    v2f acc0 = sp(0.f), acc1 = sp(0.f), accE = sp(0.f);

#pragma unroll 2
    for (int sIdx = 0; sIdx < NSUB; ++sIdx) {
        const v2f* f2 = (const v2f*)(wpack + sIdx * 96);   // 48 duplicated pairs

        v2f h[4];
#pragma unroll
        for (int j = 0; j < 4; ++j) {
            v2f s = f2[24 + j];
#pragma unroll
            for (int i = 0; i < 6; ++i)
                s = pk_fma(f2[j * 6 + i], xa[i], s);
            h[j] = tanhshrink_v(s);
        }

        v2f o0 = f2[36], o1 = f2[37];
#pragma unroll
        for (int j = 0; j < 4; ++j) {
            o0 = pk_fma(f2[28 + j], h[j], o0);
            o1 = pk_fma(f2[32 + j], h[j], o1);
        }
        o0 = tanh_pade_v(o0);
        o1 = tanh_pade_v(o1);

        // gate logit pre-scaled by log2e -> exp2 directly (needs range: trans)
        v2f la = f2[44];
#pragma unroll
        for (int j = 0; j < 6; ++j)
            la = pk_fma(f2[38 + j], ga[j], la);
        v2f ea;
        ea.x = __builtin_amdgcn_exp2f(la.x);
        ea.y = __builtin_amdgcn_exp2f(la.y);

        accE = accE + ea;
        acc0 = pk_fma(ea, o0, acc0);
        acc1 = pk_fma(ea, o1, acc1);
    }

    // final softmax normalization (amortized; exact-ish rcp via 2 Newton)
    v2f ra = pk_rcp1(accE);
    ra = ra * pk_fma(-accE, ra, sp(2.0f));   // 2nd Newton iter for safety
    acc0 = acc0 * ra;
    acc1 = acc1 * ra;

    float4 r;
    r.x = acc0.x; r.y = acc1.x; r.z = acc0.y; r.w = acc1.y;
    ((float4*)&out[t * 4])[0] = r;
}

extern "C" void kernel_launch(void* const* d_in, const int* in_sizes, int n_in,
                              void* d_out, int out_size, void* d_ws, size_t ws_size,
                              hipStream_t stream) {
    const float* x   = (const float*)d_in[0];
    const float* W1  = (const float*)d_in[1];
    const float* b1  = (const float*)d_in[2];
    const float* W2  = (const float*)d_in[3];
    const float* b2  = (const float*)d_in[4];
    const float* Gw1 = (const float*)d_in[5];
    const float* Gb1 = (const float*)d_in[6];
    const float* Gw2 = (const float*)d_in[7];
    const float* Gb2 = (const float*)d_in[8];
    float* out = (float*)d_out;
    float* ws  = (float*)d_ws;   // 64*96*4 = 24 KB

    pack_kernel<<<1, 64, 0, stream>>>(W1, b1, W2, b2, Gw2, Gb2, ws);

    const int threads = 256;
    const int blocks = (524288 / 2) / threads;  // 1024
    moe_kernel<<<blocks, threads, 0, stream>>>(x, ws, Gw1, Gb1, out);
}